// Round 10
// baseline (647.259 us; speedup 1.0000x reference)
//
#include <hip/hip_runtime.h>
#include <math.h>

#define NN 100000
#define NE 1600000
#define NBUK ((NN + 255) / 256)      // 391 buckets of 256 nodes
#define CAP 5120                     // bucket capacity (mean 4096, +16 sigma)
#define NBLK_A 500
#define EPB (NE / NBLK_A)            // 3200 edges per bin block
#define GPB (EPB / 4)                // 800 int4 groups
#define MT ((NN + 127) / 128)        // 782 M-tiles
#define MPAD ((size_t)MT * 128)      // 100096 padded rows for A operands
#define PACK_B 192                   // pack_weights blocks in front
#define FRONT_GRID 2048

typedef __attribute__((ext_vector_type(8))) short short8;
typedef __attribute__((ext_vector_type(4))) float f32x4;
typedef __attribute__((ext_vector_type(4))) int i32x4;
typedef unsigned short ushort_t;
typedef unsigned int uint_t;

__device__ inline ushort_t f2bf(float f) {  // RNE
    uint_t u = __builtin_bit_cast(uint_t, f);
    u += 0x7FFFu + ((u >> 16) & 1u);
    return (ushort_t)(u >> 16);
}
__device__ inline float bits2f(uint_t u) { return __builtin_bit_cast(float, u); }
__device__ inline float lo16(uint_t u) { return bits2f(u << 16); }
__device__ inline float hi16(uint_t u) { return bits2f(u & 0xFFFF0000u); }
__device__ inline float bf2f(ushort_t b) { return bits2f((uint_t)b << 16); }  // bare bf16 -> f32

__device__ inline void gload_lds16(const void* g, void* l) {
    __builtin_amdgcn_global_load_lds(
        (const __attribute__((address_space(1))) unsigned int*)g,
        (__attribute__((address_space(3))) unsigned int*)l, 16, 0, 0);
}

// ---------------- front: cvt x->bf16 | pack weights | init gcur (bucket bases)
__global__ __launch_bounds__(256) void front(const float* __restrict__ x,
                                             ushort_t* __restrict__ xb,
                                             const float* __restrict__ Wl1,
                                             const float* __restrict__ Wr1,
                                             const float* __restrict__ Wl2,
                                             const float* __restrict__ Wr2,
                                             ushort_t* __restrict__ W1T,
                                             ushort_t* __restrict__ W2T,
                                             int* __restrict__ gcur) {
    int bid = blockIdx.x, tid = threadIdx.x;
    if (bid == 0) {
        for (int i = tid; i < NBUK; i += 256) gcur[i] = i * CAP;
    }
    if (bid < PACK_B) {  // pack weights
        int gid = bid * 256 + tid;
        if (gid < 256 * 128) {
            int n = gid >> 7, k = gid & 127;
            float v = (n < 128) ? Wl1[k * 128 + n] : Wr1[k * 128 + (n - 128)];
            W1T[gid] = f2bf(v);
        } else {
            int g = gid - 256 * 128;
            if (g < 128 * 128) {
                int n = g >> 7, k = g & 127;
                float v = 0.0f;
                if (n < 40)      v = Wl2[k * 40 + n];
                else if (n < 80) v = Wr2[k * 40 + (n - 40)];
                W2T[g] = f2bf(v);
            }
        }
    } else {  // cvt x -> bf16, grid-stride over remaining blocks
        const int total = NN * 128 / 8;
        const int nb = FRONT_GRID - PACK_B;
        const f32x4* src = (const f32x4*)x;
        for (int g = (bid - PACK_B) * 256 + tid; g < total; g += nb * 256) {
            f32x4 v0 = __builtin_nontemporal_load(src + (size_t)g * 2);
            f32x4 v1 = __builtin_nontemporal_load(src + (size_t)g * 2 + 1);
            i32x4 o;
            o[0] = ((uint_t)f2bf(v0[1]) << 16) | (uint_t)f2bf(v0[0]);
            o[1] = ((uint_t)f2bf(v0[3]) << 16) | (uint_t)f2bf(v0[2]);
            o[2] = ((uint_t)f2bf(v1[1]) << 16) | (uint_t)f2bf(v1[0]);
            o[3] = ((uint_t)f2bf(v1[3]) << 16) | (uint_t)f2bf(v1[2]);
            *(i32x4*)(xb + (size_t)g * 8) = o;
        }
    }
}

// ---------------- CSR: bin edges into PADDED bucket runs (stride CAP).
__global__ __launch_bounds__(256) void bin_pass(const int* __restrict__ ei,
                                                int* __restrict__ gcur,
                                                int* __restrict__ pairs) {
    __shared__ int h[NBUK];
    __shared__ int base[NBUK];
    int bid = blockIdx.x, tid = threadIdx.x;
    for (int i = tid; i < NBUK; i += 256) h[i] = 0;
    __syncthreads();
    int e0 = bid * EPB;
    const i32x4* dsts = (const i32x4*)(ei + NE + e0);
    const i32x4* srcs = (const i32x4*)(ei + e0);
    for (int g = tid; g < GPB; g += 256) {
        i32x4 d = __builtin_nontemporal_load(dsts + g);
#pragma unroll
        for (int j = 0; j < 4; ++j) atomicAdd(&h[d[j] >> 8], 1);
    }
    __syncthreads();
    for (int i = tid; i < NBUK; i += 256) {
        int c = h[i];
        base[i] = c ? atomicAdd(&gcur[i], c) : 0;
        h[i] = 0;  // reuse as run cursor
    }
    __syncthreads();
    for (int g = tid; g < GPB; g += 256) {
        i32x4 d = __builtin_nontemporal_load(dsts + g);
        i32x4 s = __builtin_nontemporal_load(srcs + g);
#pragma unroll
        for (int j = 0; j < 4; ++j) {
            int buk = d[j] >> 8;
            int pos = base[buk] + atomicAdd(&h[buk], 1);
            if (pos < (buk + 1) * CAP) pairs[pos] = (s[j] << 8) | (d[j] & 255);
        }
    }
}

// ---------------- layer-1 GEMM tile body
__device__ inline void gemm1_tile(char* As, char* Bs,
                                  const ushort_t* __restrict__ A,
                                  const ushort_t* __restrict__ Bt,
                                  ushort_t* __restrict__ G,
                                  ushort_t* __restrict__ Croot,
                                  int bx, int by, int tid) {
    int lane = tid & 63, wid = tid >> 6;
    int quad = lane >> 4, l15 = lane & 15;
    int wm = (wid & 1) * 64, wn = (wid >> 1) * 64;
    int mBase = bx * 128, nBase = by * 128;

    const char* aT = (const char*)(A + (size_t)mBase * 128);
    const char* bT = (const char*)(Bt + (size_t)nBase * 128);
#pragma unroll
    for (int ii = 0; ii < 8; ++ii) {
        int rr = (wid * 8 + ii) * 4 + quad;
        int src = rr * 256 + ((l15 * 16) ^ ((rr & 7) << 4));
        int ldsb = (wid * 8 + ii) * 1024;
        gload_lds16(aT + src, As + ldsb);
        gload_lds16(bT + src, Bs + ldsb);
    }
    asm volatile("s_waitcnt vmcnt(0)" ::: "memory");
    __syncthreads();

    f32x4 acc[4][4];
#pragma unroll
    for (int i = 0; i < 4; ++i)
#pragma unroll
        for (int j = 0; j < 4; ++j) acc[i][j] = (f32x4){0.f, 0.f, 0.f, 0.f};

#pragma unroll
    for (int kk = 0; kk < 4; ++kk) {
        int kByte = kk * 64 + quad * 16;
        short8 af[4], bfr[4];
#pragma unroll
        for (int i = 0; i < 4; ++i) {
            int row = wm + i * 16 + l15;
            af[i] = *(const short8*)(As + row * 256 + (kByte ^ ((row & 7) << 4)));
        }
#pragma unroll
        for (int j = 0; j < 4; ++j) {
            int row = wn + j * 16 + l15;
            bfr[j] = *(const short8*)(Bs + row * 256 + (kByte ^ ((row & 7) << 4)));
        }
#pragma unroll
        for (int i = 0; i < 4; ++i)
#pragma unroll
            for (int j = 0; j < 4; ++j)
                acc[i][j] = __builtin_amdgcn_mfma_f32_16x16x32_bf16(af[i], bfr[j],
                                                                    acc[i][j], 0, 0, 0);
    }

#pragma unroll
    for (int i = 0; i < 4; ++i) {
#pragma unroll
        for (int r = 0; r < 4; ++r) {
            int m = mBase + wm + i * 16 + quad * 4 + r;
            if (m >= NN) continue;
#pragma unroll
            for (int j = 0; j < 4; ++j) {
                int n = nBase + wn + j * 16 + l15;
                float v = acc[i][j][r];
                if (n < 128) G[(size_t)m * 128 + n] = f2bf(v);
                else Croot[(size_t)m * 128 + (n - 128)] = f2bf(v);
            }
        }
    }
}

// ---------------- MERGED: per-bucket counting sort + layer-1 GEMM
__global__ __launch_bounds__(256, 2) void sort_gemm1(const int* __restrict__ gcur,
                                                     const int* __restrict__ pairs,
                                                     int* __restrict__ starts,
                                                     int* __restrict__ ends,
                                                     int* __restrict__ ssrc,
                                                     const ushort_t* __restrict__ A,
                                                     const ushort_t* __restrict__ Bt,
                                                     ushort_t* __restrict__ G,
                                                     ushort_t* __restrict__ Croot) {
    __shared__ __align__(16) char smem[65536];
    int bid = blockIdx.x, tid = threadIdx.x;
    if (bid < NBUK) {
        int* plds = (int*)smem;                 // CAP ints
        int* slds = (int*)(smem + CAP * 4);     // CAP ints
        int* cnt  = (int*)(smem + CAP * 8);     // 256 ints
        int* excl = cnt + 256;                  // 256 ints
        int buk = bid;
        int bstart = buk * CAP;
        int count = min(gcur[buk] - bstart, CAP);
        int lo = buk << 8;
        cnt[tid] = 0;
        __syncthreads();
        for (int j = tid; j < count; j += 256) {
            int p = pairs[bstart + j];
            plds[j] = p;
            atomicAdd(&cnt[p & 255], 1);
        }
        __syncthreads();
        int c = cnt[tid];
        excl[tid] = c;
        __syncthreads();
        for (int d = 1; d < 256; d <<= 1) {
            int tmp = (tid >= d) ? excl[tid - d] : 0;
            __syncthreads();
            excl[tid] += tmp;
            __syncthreads();
        }
        int myExcl = excl[tid] - c;
        __syncthreads();
        excl[tid] = myExcl;
        cnt[tid] = 0;  // reuse as scatter cursor
        __syncthreads();
        for (int j = tid; j < count; j += 256) {
            int p = plds[j];
            int loc = p & 255;
            int pos = excl[loc] + atomicAdd(&cnt[loc], 1);
            slds[pos] = p >> 8;
        }
        __syncthreads();
        for (int j = tid; j < count; j += 256) ssrc[bstart + j] = slds[j];
        if (lo + tid < NN) {
            starts[lo + tid] = bstart + myExcl;
            ends[lo + tid]   = bstart + myExcl + c;
        }
    } else {
        int gb = bid - NBUK;
        int bx = gb % MT, by = gb / MT;
        gemm1_tile(smem, smem + 32768, A, Bt, G, Croot, bx, by, tid);
    }
}

// ---------------- FUSED aggregate layer 1 + per-node layer-2 matvec.
__global__ __launch_bounds__(256) void aggregate1f(const int* __restrict__ starts,
                                                   const int* __restrict__ ends,
                                                   const int* __restrict__ ssrc,
                                                   const ushort_t* __restrict__ G1,
                                                   const ushort_t* __restrict__ C1root,
                                                   const float* __restrict__ b1,
                                                   const ushort_t* __restrict__ W2T,
                                                   ushort_t* __restrict__ G2a,
                                                   ushort_t* __restrict__ G2b,
                                                   ushort_t* __restrict__ C2root) {
    int w = (blockIdx.x * blockDim.x + threadIdx.x) >> 6;
    int lane = threadIdx.x & 63;
    if (w >= NN) return;
    int start = starts[w], end = ends[w];
    int g = lane >> 4, q = lane & 15;
    const char* Gb = (const char*)G1;
    int qb = q << 4;  // byte offset within row
    float a0 = 0.f, a1 = 0.f, a2 = 0.f, a3 = 0.f, a4 = 0.f, a5 = 0.f, a6 = 0.f, a7 = 0.f;
    for (int base = start; base < end; base += 64) {
        int cnt = min(64, end - base);
        int idx = (base + lane < end) ? ssrc[base + lane] : 0;
        int j = 0;
        for (; j + 16 <= cnt; j += 16) {  // 16 edges: 4 gathers in flight
            int s0 = __shfl(idx, j + g, 64);
            int s1 = __shfl(idx, j + 4 + g, 64);
            int s2 = __shfl(idx, j + 8 + g, 64);
            int s3 = __shfl(idx, j + 12 + g, 64);
            uint4 u0 = *(const uint4*)(Gb + (s0 << 8) + qb);
            uint4 u1 = *(const uint4*)(Gb + (s1 << 8) + qb);
            uint4 u2 = *(const uint4*)(Gb + (s2 << 8) + qb);
            uint4 u3 = *(const uint4*)(Gb + (s3 << 8) + qb);
            a0 += (lo16(u0.x) + lo16(u1.x)) + (lo16(u2.x) + lo16(u3.x));
            a1 += (hi16(u0.x) + hi16(u1.x)) + (hi16(u2.x) + hi16(u3.x));
            a2 += (lo16(u0.y) + lo16(u1.y)) + (lo16(u2.y) + lo16(u3.y));
            a3 += (hi16(u0.y) + hi16(u1.y)) + (hi16(u2.y) + hi16(u3.y));
            a4 += (lo16(u0.z) + lo16(u1.z)) + (lo16(u2.z) + lo16(u3.z));
            a5 += (hi16(u0.z) + hi16(u1.z)) + (hi16(u2.z) + hi16(u3.z));
            a6 += (lo16(u0.w) + lo16(u1.w)) + (lo16(u2.w) + lo16(u3.w));
            a7 += (hi16(u0.w) + hi16(u1.w)) + (hi16(u2.w) + hi16(u3.w));
        }
        for (; j + 8 <= cnt; j += 8) {  // 8 edges: 2 gathers in flight
            int s0 = __shfl(idx, j + g, 64);
            int s1 = __shfl(idx, j + 4 + g, 64);
            uint4 u0 = *(const uint4*)(Gb + (s0 << 8) + qb);
            uint4 u1 = *(const uint4*)(Gb + (s1 << 8) + qb);
            a0 += lo16(u0.x) + lo16(u1.x);
            a1 += hi16(u0.x) + hi16(u1.x);
            a2 += lo16(u0.y) + lo16(u1.y);
            a3 += hi16(u0.y) + hi16(u1.y);
            a4 += lo16(u0.z) + lo16(u1.z);
            a5 += hi16(u0.z) + hi16(u1.z);
            a6 += lo16(u0.w) + lo16(u1.w);
            a7 += hi16(u0.w) + hi16(u1.w);
        }
        for (; j < cnt; j += 4) {  // tail: up to 4 edges, predicated per group
            int e = j + g;
            int s0 = __shfl(idx, (e < cnt) ? e : 0, 64);
            if (e < cnt) {
                uint4 u0 = *(const uint4*)(Gb + (s0 << 8) + qb);
                a0 += lo16(u0.x); a1 += hi16(u0.x);
                a2 += lo16(u0.y); a3 += hi16(u0.y);
                a4 += lo16(u0.z); a5 += hi16(u0.z);
                a6 += lo16(u0.w); a7 += hi16(u0.w);
            }
        }
    }
    a0 += __shfl_xor(a0, 16, 64); a0 += __shfl_xor(a0, 32, 64);
    a1 += __shfl_xor(a1, 16, 64); a1 += __shfl_xor(a1, 32, 64);
    a2 += __shfl_xor(a2, 16, 64); a2 += __shfl_xor(a2, 32, 64);
    a3 += __shfl_xor(a3, 16, 64); a3 += __shfl_xor(a3, 32, 64);
    a4 += __shfl_xor(a4, 16, 64); a4 += __shfl_xor(a4, 32, 64);
    a5 += __shfl_xor(a5, 16, 64); a5 += __shfl_xor(a5, 32, 64);
    a6 += __shfl_xor(a6, 16, 64); a6 += __shfl_xor(a6, 32, 64);
    a7 += __shfl_xor(a7, 16, 64); a7 += __shfl_xor(a7, 32, 64);

    // h on ALL lanes (same-q lanes identical -> shfl broadcast below)
    float inv = 1.0f / fmaxf((float)(end - start), 1.0f);
    uint4 rv = *(const uint4*)((const char*)C1root + (size_t)w * 256 + qb);
    float4 c0 = *(const float4*)(b1 + q * 8);
    float4 c1 = *(const float4*)(b1 + q * 8 + 4);
    // bf16-round h (matches old s1b storage rounding): bf2f(f2bf(x))
    float hf0 = bf2f(f2bf(fmaxf(a0 * inv + c0.x + lo16(rv.x), 0.f)));
    float hf1 = bf2f(f2bf(fmaxf(a1 * inv + c0.y + hi16(rv.x), 0.f)));
    float hf2 = bf2f(f2bf(fmaxf(a2 * inv + c0.z + lo16(rv.y), 0.f)));
    float hf3 = bf2f(f2bf(fmaxf(a3 * inv + c0.w + hi16(rv.y), 0.f)));
    float hf4 = bf2f(f2bf(fmaxf(a4 * inv + c1.x + lo16(rv.z), 0.f)));
    float hf5 = bf2f(f2bf(fmaxf(a5 * inv + c1.y + hi16(rv.z), 0.f)));
    float hf6 = bf2f(f2bf(fmaxf(a6 * inv + c1.z + lo16(rv.w), 0.f)));
    float hf7 = bf2f(f2bf(fmaxf(a7 * inv + c1.w + hi16(rv.w), 0.f)));

    // per-node layer-2 matvec: lane computes n_lo = lane, n_hi = 64 + q
    float accL = 0.f, accH = 0.f;
    const ushort_t* WrowL = W2T + (size_t)lane * 128;
    const ushort_t* WrowH = W2T + (size_t)(64 + q) * 128;
#pragma unroll
    for (int kq = 0; kq < 16; ++kq) {
        float hb0 = __shfl(hf0, kq, 64), hb1 = __shfl(hf1, kq, 64);
        float hb2 = __shfl(hf2, kq, 64), hb3 = __shfl(hf3, kq, 64);
        float hb4 = __shfl(hf4, kq, 64), hb5 = __shfl(hf5, kq, 64);
        float hb6 = __shfl(hf6, kq, 64), hb7 = __shfl(hf7, kq, 64);
        short8 wl = *(const short8*)(WrowL + kq * 8);
        short8 wh = *(const short8*)(WrowH + kq * 8);
        accL += hb0 * bf2f((ushort_t)wl[0]) + hb1 * bf2f((ushort_t)wl[1])
              + hb2 * bf2f((ushort_t)wl[2]) + hb3 * bf2f((ushort_t)wl[3])
              + hb4 * bf2f((ushort_t)wl[4]) + hb5 * bf2f((ushort_t)wl[5])
              + hb6 * bf2f((ushort_t)wl[6]) + hb7 * bf2f((ushort_t)wl[7]);
        accH += hb0 * bf2f((ushort_t)wh[0]) + hb1 * bf2f((ushort_t)wh[1])
              + hb2 * bf2f((ushort_t)wh[2]) + hb3 * bf2f((ushort_t)wh[3])
              + hb4 * bf2f((ushort_t)wh[4]) + hb5 * bf2f((ushort_t)wh[5])
              + hb6 * bf2f((ushort_t)wh[6]) + hb7 * bf2f((ushort_t)wh[7]);
    }
    // scatter: n<32 -> G2a; 32..39 -> G2b; 40..79 -> C2root
    if (lane < 32) G2a[(size_t)w * 32 + lane] = f2bf(accL);
    else if (lane < 40) G2b[(size_t)w * 8 + (lane - 32)] = f2bf(accL);
    else C2root[(size_t)w * 40 + (lane - 40)] = f2bf(accL);
    if (lane < 16) C2root[(size_t)w * 40 + 24 + lane] = f2bf(accH);
}

// ---------------- aggregate layer 2 + log_softmax
__global__ __launch_bounds__(256) void aggregate2(const int* __restrict__ starts,
                                                  const int* __restrict__ ends,
                                                  const int* __restrict__ ssrc,
                                                  const ushort_t* __restrict__ G2a,
                                                  const ushort_t* __restrict__ G2b,
                                                  const ushort_t* __restrict__ C2root,
                                                  const float* __restrict__ b2,
                                                  float* __restrict__ out) {
    int w = (blockIdx.x * blockDim.x + threadIdx.x) >> 6;
    int lane = threadIdx.x & 63;
    if (w >= NN) return;
    int start = starts[w], end = ends[w];
    int g = lane >> 4, q = lane & 15;
    bool act = q < 10;
    const char* tbl;
    int rsh, off0;
    if (q < 8) { tbl = (const char*)G2a; rsh = 6; off0 = q * 8; }
    else       { tbl = (const char*)G2b; rsh = 4; off0 = (q - 8) * 8; }
    float a0 = 0.f, a1 = 0.f, a2 = 0.f, a3 = 0.f;
    for (int base = start; base < end; base += 64) {
        int cnt = min(64, end - base);
        int idx = (base + lane < end) ? ssrc[base + lane] : 0;
        int j = 0;
        for (; j + 16 <= cnt; j += 16) {
            int s0 = __shfl(idx, j + g, 64);
            int s1 = __shfl(idx, j + 4 + g, 64);
            int s2 = __shfl(idx, j + 8 + g, 64);
            int s3 = __shfl(idx, j + 12 + g, 64);
            if (act) {
                uint2 u0 = *(const uint2*)(tbl + ((size_t)s0 << rsh) + off0);
                uint2 u1 = *(const uint2*)(tbl + ((size_t)s1 << rsh) + off0);
                uint2 u2 = *(const uint2*)(tbl + ((size_t)s2 << rsh) + off0);
                uint2 u3 = *(const uint2*)(tbl + ((size_t)s3 << rsh) + off0);
                a0 += (lo16(u0.x) + lo16(u1.x)) + (lo16(u2.x) + lo16(u3.x));
                a1 += (hi16(u0.x) + hi16(u1.x)) + (hi16(u2.x) + hi16(u3.x));
                a2 += (lo16(u0.y) + lo16(u1.y)) + (lo16(u2.y) + lo16(u3.y));
                a3 += (hi16(u0.y) + hi16(u1.y)) + (hi16(u2.y) + hi16(u3.y));
            }
        }
        for (; j + 8 <= cnt; j += 8) {
            int s0 = __shfl(idx, j + g, 64);
            int s1 = __shfl(idx, j + 4 + g, 64);
            if (act) {
                uint2 u0 = *(const uint2*)(tbl + ((size_t)s0 << rsh) + off0);
                uint2 u1 = *(const uint2*)(tbl + ((size_t)s1 << rsh) + off0);
                a0 += lo16(u0.x) + lo16(u1.x);
                a1 += hi16(u0.x) + hi16(u1.x);
                a2 += lo16(u0.y) + lo16(u1.y);
                a3 += hi16(u0.y) + hi16(u1.y);
            }
        }
        for (; j < cnt; j += 4) {
            int e = j + g;
            int s0 = __shfl(idx, (e < cnt) ? e : 0, 64);
            if (act && e < cnt) {
                uint2 u0 = *(const uint2*)(tbl + ((size_t)s0 << rsh) + off0);
                a0 += lo16(u0.x); a1 += hi16(u0.x);
                a2 += lo16(u0.y); a3 += hi16(u0.y);
            }
        }
    }
    a0 += __shfl_xor(a0, 16, 64); a0 += __shfl_xor(a0, 32, 64);
    a1 += __shfl_xor(a1, 16, 64); a1 += __shfl_xor(a1, 32, 64);
    a2 += __shfl_xor(a2, 16, 64); a2 += __shfl_xor(a2, 32, 64);
    a3 += __shfl_xor(a3, 16, 64); a3 += __shfl_xor(a3, 32, 64);
    if (g == 0) {
        float inv = 1.0f / fmaxf((float)(end - start), 1.0f);
        float v0 = -INFINITY, v1 = -INFINITY, v2 = -INFINITY, v3 = -INFINITY;
        if (act) {
            uint2 rv = *(const uint2*)((const char*)C2root + (size_t)w * 80 + (q << 3));
            float4 bb = *(const float4*)(b2 + q * 4);
            v0 = a0 * inv + bb.x + lo16(rv.x);
            v1 = a1 * inv + bb.y + hi16(rv.x);
            v2 = a2 * inv + bb.z + lo16(rv.y);
            v3 = a3 * inv + bb.w + hi16(rv.y);
        }
        float m = fmaxf(fmaxf(v0, v1), fmaxf(v2, v3));
#pragma unroll
        for (int d = 8; d >= 1; d >>= 1) m = fmaxf(m, __shfl_xor(m, d, 64));
        float e = act ? (expf(v0 - m) + expf(v1 - m)) + (expf(v2 - m) + expf(v3 - m)) : 0.f;
#pragma unroll
        for (int d = 8; d >= 1; d >>= 1) e += __shfl_xor(e, d, 64);
        float lse = m + logf(e);
        if (act) {
            float4 o = make_float4(v0 - lse, v1 - lse, v2 - lse, v3 - lse);
            *(float4*)(out + (size_t)w * 40 + q * 4) = o;
        }
    }
}

extern "C" void kernel_launch(void* const* d_in, const int* in_sizes, int n_in,
                              void* d_out, int out_size, void* d_ws, size_t ws_size,
                              hipStream_t stream) {
    const float* x   = (const float*)d_in[0];
    const int*   ei  = (const int*)d_in[1];
    const float* Wl1 = (const float*)d_in[2];
    const float* b1  = (const float*)d_in[3];
    const float* Wr1 = (const float*)d_in[4];
    const float* Wl2 = (const float*)d_in[5];
    const float* b2  = (const float*)d_in[6];
    const float* Wr2 = (const float*)d_in[7];
    float* out = (float*)d_out;

    char* ws = (char*)d_ws;
    size_t off = 0;
    auto alloc = [&](size_t bytes) -> void* {
        void* p = ws + off;
        off = (off + bytes + 255) & ~(size_t)255;
        return p;
    };
    int*      gcur    = (int*)alloc((size_t)NBUK * 4);
    int*      pairs   = (int*)alloc((size_t)NBUK * CAP * 4);   // padded buckets
    int*      starts  = (int*)alloc((size_t)NN * 4);
    int*      ends    = (int*)alloc((size_t)NN * 4);
    int*      ssrc    = (int*)alloc((size_t)NBUK * CAP * 4);   // padded buckets
    ushort_t* W1T     = (ushort_t*)alloc((size_t)256 * 128 * 2);
    ushort_t* W2T     = (ushort_t*)alloc((size_t)128 * 128 * 2);
    ushort_t* xb      = (ushort_t*)alloc(MPAD * 128 * 2);      // x in bf16, padded rows
    ushort_t* G1      = (ushort_t*)alloc((size_t)NN * 128 * 2);
    ushort_t* C1root  = (ushort_t*)alloc((size_t)NN * 128 * 2);
    ushort_t* G2a     = (ushort_t*)alloc((size_t)NN * 32 * 2); // ch 0-31, 64B rows
    ushort_t* G2b     = (ushort_t*)alloc((size_t)NN * 8 * 2);  // ch 32-39, 16B rows
    ushort_t* C2root  = (ushort_t*)alloc((size_t)NN * 40 * 2);

    front<<<FRONT_GRID, 256, 0, stream>>>(x, xb, Wl1, Wr1, Wl2, Wr2, W1T, W2T, gcur);
    bin_pass<<<NBLK_A, 256, 0, stream>>>(ei, gcur, pairs);
    sort_gemm1<<<NBUK + MT * 2, 256, 0, stream>>>(gcur, pairs, starts, ends, ssrc,
                                                  xb, W1T, G1, C1root);
    aggregate1f<<<(NN * 64 + 255) / 256, 256, 0, stream>>>(starts, ends, ssrc, G1, C1root,
                                                           b1, W2T, G2a, G2b, C2root);
    aggregate2<<<(NN * 64 + 255) / 256, 256, 0, stream>>>(starts, ends, ssrc, G2a, G2b,
                                                          C2root, b2, out);
}

// Round 11
// 299.668 us; speedup vs baseline: 2.1599x; 2.1599x over previous
//
#include <hip/hip_runtime.h>
#include <math.h>

#define NN 100000
#define NE 1600000
#define NBUK ((NN + 255) / 256)      // 391 buckets of 256 nodes
#define CAP 5120                     // bucket capacity (mean 4096, +16 sigma)
#define NBLK_A 500
#define EPB (NE / NBLK_A)            // 3200 edges per bin block
#define GPB (EPB / 4)                // 800 int4 groups
#define MT ((NN + 127) / 128)        // 782 M-tiles
#define MPAD ((size_t)MT * 128)      // 100096 padded rows for A operands
#define PACK_B 192                   // pack_weights blocks in front
#define FRONT_GRID 2048

typedef __attribute__((ext_vector_type(8))) short short8;
typedef __attribute__((ext_vector_type(4))) float f32x4;
typedef __attribute__((ext_vector_type(4))) int i32x4;
typedef unsigned short ushort_t;
typedef unsigned int uint_t;

__device__ inline ushort_t f2bf(float f) {  // RNE
    uint_t u = __builtin_bit_cast(uint_t, f);
    u += 0x7FFFu + ((u >> 16) & 1u);
    return (ushort_t)(u >> 16);
}
__device__ inline float bits2f(uint_t u) { return __builtin_bit_cast(float, u); }
__device__ inline float lo16(uint_t u) { return bits2f(u << 16); }
__device__ inline float hi16(uint_t u) { return bits2f(u & 0xFFFF0000u); }

__device__ inline void gload_lds16(const void* g, void* l) {
    __builtin_amdgcn_global_load_lds(
        (const __attribute__((address_space(1))) unsigned int*)g,
        (__attribute__((address_space(3))) unsigned int*)l, 16, 0, 0);
}

// ---------------- front: cvt x->bf16 | pack weights | init gcur (bucket bases)
__global__ __launch_bounds__(256) void front(const float* __restrict__ x,
                                             ushort_t* __restrict__ xb,
                                             const float* __restrict__ Wl1,
                                             const float* __restrict__ Wr1,
                                             const float* __restrict__ Wl2,
                                             const float* __restrict__ Wr2,
                                             ushort_t* __restrict__ W1T,
                                             ushort_t* __restrict__ W2T,
                                             int* __restrict__ gcur) {
    int bid = blockIdx.x, tid = threadIdx.x;
    if (bid == 0) {
        for (int i = tid; i < NBUK; i += 256) gcur[i] = i * CAP;
    }
    if (bid < PACK_B) {  // pack weights
        int gid = bid * 256 + tid;
        if (gid < 256 * 128) {
            int n = gid >> 7, k = gid & 127;
            float v = (n < 128) ? Wl1[k * 128 + n] : Wr1[k * 128 + (n - 128)];
            W1T[gid] = f2bf(v);
        } else {
            int g = gid - 256 * 128;
            if (g < 128 * 128) {
                int n = g >> 7, k = g & 127;
                float v = 0.0f;
                if (n < 40)      v = Wl2[k * 40 + n];
                else if (n < 80) v = Wr2[k * 40 + (n - 40)];
                W2T[g] = f2bf(v);
            }
        }
    } else {  // cvt x -> bf16, grid-stride over remaining blocks
        const int total = NN * 128 / 8;
        const int nb = FRONT_GRID - PACK_B;
        const f32x4* src = (const f32x4*)x;
        for (int g = (bid - PACK_B) * 256 + tid; g < total; g += nb * 256) {
            f32x4 v0 = __builtin_nontemporal_load(src + (size_t)g * 2);
            f32x4 v1 = __builtin_nontemporal_load(src + (size_t)g * 2 + 1);
            i32x4 o;
            o[0] = ((uint_t)f2bf(v0[1]) << 16) | (uint_t)f2bf(v0[0]);
            o[1] = ((uint_t)f2bf(v0[3]) << 16) | (uint_t)f2bf(v0[2]);
            o[2] = ((uint_t)f2bf(v1[1]) << 16) | (uint_t)f2bf(v1[0]);
            o[3] = ((uint_t)f2bf(v1[3]) << 16) | (uint_t)f2bf(v1[2]);
            *(i32x4*)(xb + (size_t)g * 8) = o;
        }
    }
}

// ---------------- CSR: bin edges into PADDED bucket runs (stride CAP).
__global__ __launch_bounds__(256) void bin_pass(const int* __restrict__ ei,
                                                int* __restrict__ gcur,
                                                int* __restrict__ pairs) {
    __shared__ int h[NBUK];
    __shared__ int base[NBUK];
    int bid = blockIdx.x, tid = threadIdx.x;
    for (int i = tid; i < NBUK; i += 256) h[i] = 0;
    __syncthreads();
    int e0 = bid * EPB;
    const i32x4* dsts = (const i32x4*)(ei + NE + e0);
    const i32x4* srcs = (const i32x4*)(ei + e0);
    for (int g = tid; g < GPB; g += 256) {
        i32x4 d = __builtin_nontemporal_load(dsts + g);
#pragma unroll
        for (int j = 0; j < 4; ++j) atomicAdd(&h[d[j] >> 8], 1);
    }
    __syncthreads();
    for (int i = tid; i < NBUK; i += 256) {
        int c = h[i];
        base[i] = c ? atomicAdd(&gcur[i], c) : 0;
        h[i] = 0;  // reuse as run cursor
    }
    __syncthreads();
    for (int g = tid; g < GPB; g += 256) {
        i32x4 d = __builtin_nontemporal_load(dsts + g);
        i32x4 s = __builtin_nontemporal_load(srcs + g);
#pragma unroll
        for (int j = 0; j < 4; ++j) {
            int buk = d[j] >> 8;
            int pos = base[buk] + atomicAdd(&h[buk], 1);
            if (pos < (buk + 1) * CAP) pairs[pos] = (s[j] << 8) | (d[j] & 255);
        }
    }
}

// ---------------- shared GEMM tile: A[128,K=128]bf16 @ Bt^T, one-shot LDS stage.
//   LAYER 1: n<128 -> O0 stride 128; n<256 -> Croot stride 128
//   LAYER 2: n<32 -> O0 (G2a, stride 32); n<40 -> O1 (G2b, stride 8); n<80 -> Croot stride 40
template <int LAYER>
__device__ inline void gemm_tile(char* As, char* Bs,
                                 const ushort_t* __restrict__ A,
                                 const ushort_t* __restrict__ Bt,
                                 ushort_t* __restrict__ O0,
                                 ushort_t* __restrict__ O1,
                                 ushort_t* __restrict__ Croot,
                                 int bx, int by, int tid) {
    int lane = tid & 63, wid = tid >> 6;
    int quad = lane >> 4, l15 = lane & 15;
    int wm = (wid & 1) * 64, wn = (wid >> 1) * 64;
    int mBase = bx * 128, nBase = by * 128;

    const char* aT = (const char*)(A + (size_t)mBase * 128);
    const char* bT = (const char*)(Bt + (size_t)nBase * 128);
#pragma unroll
    for (int ii = 0; ii < 8; ++ii) {
        int rr = (wid * 8 + ii) * 4 + quad;
        int src = rr * 256 + ((l15 * 16) ^ ((rr & 7) << 4));
        int ldsb = (wid * 8 + ii) * 1024;
        gload_lds16(aT + src, As + ldsb);
        gload_lds16(bT + src, Bs + ldsb);
    }
    asm volatile("s_waitcnt vmcnt(0)" ::: "memory");
    __syncthreads();

    f32x4 acc[4][4];
#pragma unroll
    for (int i = 0; i < 4; ++i)
#pragma unroll
        for (int j = 0; j < 4; ++j) acc[i][j] = (f32x4){0.f, 0.f, 0.f, 0.f};

#pragma unroll
    for (int kk = 0; kk < 4; ++kk) {
        int kByte = kk * 64 + quad * 16;
        short8 af[4], bfr[4];
#pragma unroll
        for (int i = 0; i < 4; ++i) {
            int row = wm + i * 16 + l15;
            af[i] = *(const short8*)(As + row * 256 + (kByte ^ ((row & 7) << 4)));
        }
#pragma unroll
        for (int j = 0; j < 4; ++j) {
            int row = wn + j * 16 + l15;
            bfr[j] = *(const short8*)(Bs + row * 256 + (kByte ^ ((row & 7) << 4)));
        }
#pragma unroll
        for (int i = 0; i < 4; ++i)
#pragma unroll
            for (int j = 0; j < 4; ++j)
                acc[i][j] = __builtin_amdgcn_mfma_f32_16x16x32_bf16(af[i], bfr[j],
                                                                    acc[i][j], 0, 0, 0);
    }

#pragma unroll
    for (int i = 0; i < 4; ++i) {
#pragma unroll
        for (int r = 0; r < 4; ++r) {
            int m = mBase + wm + i * 16 + quad * 4 + r;
            if (m >= NN) continue;
#pragma unroll
            for (int j = 0; j < 4; ++j) {
                int n = nBase + wn + j * 16 + l15;
                float v = acc[i][j][r];
                if (LAYER == 1) {
                    if (n < 128) O0[(size_t)m * 128 + n] = f2bf(v);
                    else O1[(size_t)m * 128 + (n - 128)] = f2bf(v);
                } else {
                    if (n < 32) O0[(size_t)m * 32 + n] = f2bf(v);
                    else if (n < 40) O1[(size_t)m * 8 + (n - 32)] = f2bf(v);
                    else if (n < 80) Croot[(size_t)m * 40 + (n - 40)] = f2bf(v);
                }
            }
        }
    }
}

// ---------------- MERGED: per-bucket counting sort + layer-1 GEMM
__global__ __launch_bounds__(256, 2) void sort_gemm1(const int* __restrict__ gcur,
                                                     const int* __restrict__ pairs,
                                                     int* __restrict__ starts,
                                                     int* __restrict__ ends,
                                                     int* __restrict__ ssrc,
                                                     const ushort_t* __restrict__ A,
                                                     const ushort_t* __restrict__ Bt,
                                                     ushort_t* __restrict__ G,
                                                     ushort_t* __restrict__ Croot) {
    __shared__ __align__(16) char smem[65536];
    int bid = blockIdx.x, tid = threadIdx.x;
    if (bid < NBUK) {
        int* plds = (int*)smem;                 // CAP ints
        int* slds = (int*)(smem + CAP * 4);     // CAP ints
        int* cnt  = (int*)(smem + CAP * 8);     // 256 ints
        int* excl = cnt + 256;                  // 256 ints
        int buk = bid;
        int bstart = buk * CAP;
        int count = min(gcur[buk] - bstart, CAP);
        int lo = buk << 8;
        cnt[tid] = 0;
        __syncthreads();
        for (int j = tid; j < count; j += 256) {
            int p = pairs[bstart + j];
            plds[j] = p;
            atomicAdd(&cnt[p & 255], 1);
        }
        __syncthreads();
        int c = cnt[tid];
        excl[tid] = c;
        __syncthreads();
        for (int d = 1; d < 256; d <<= 1) {
            int tmp = (tid >= d) ? excl[tid - d] : 0;
            __syncthreads();
            excl[tid] += tmp;
            __syncthreads();
        }
        int myExcl = excl[tid] - c;
        __syncthreads();
        excl[tid] = myExcl;
        cnt[tid] = 0;  // reuse as scatter cursor
        __syncthreads();
        for (int j = tid; j < count; j += 256) {
            int p = plds[j];
            int loc = p & 255;
            int pos = excl[loc] + atomicAdd(&cnt[loc], 1);
            slds[pos] = p >> 8;
        }
        __syncthreads();
        for (int j = tid; j < count; j += 256) ssrc[bstart + j] = slds[j];
        if (lo + tid < NN) {
            starts[lo + tid] = bstart + myExcl;
            ends[lo + tid]   = bstart + myExcl + c;
        }
    } else {
        int gb = bid - NBUK;
        int bx = gb % MT, by = gb / MT;
        gemm_tile<1>(smem, smem + 32768, A, Bt, G, Croot, (ushort_t*)nullptr, bx, by, tid);
    }
}

// ---------------- layer-2 GEMM (split G2a/G2b output)
__global__ __launch_bounds__(256, 2) void gemm2_k(const ushort_t* __restrict__ A,
                                                  const ushort_t* __restrict__ Bt,
                                                  ushort_t* __restrict__ G2a,
                                                  ushort_t* __restrict__ G2b,
                                                  ushort_t* __restrict__ C2root) {
    __shared__ __align__(16) char smem[65536];
    gemm_tile<2>(smem, smem + 32768, A, Bt, G2a, G2b, C2root, blockIdx.x, 0, threadIdx.x);
}

// ---------------- aggregate layer 1: QUARTER-WAVE edge parallelism (32 VGPR,
// occupancy-preserving — the ONLY asset of the pinned gather is TLP).
__global__ __launch_bounds__(256) void aggregate1(const int* __restrict__ starts,
                                                  const int* __restrict__ ends,
                                                  const int* __restrict__ ssrc,
                                                  const ushort_t* __restrict__ G1,
                                                  const ushort_t* __restrict__ C1root,
                                                  const float* __restrict__ b1,
                                                  ushort_t* __restrict__ s1b) {
    int w = (blockIdx.x * blockDim.x + threadIdx.x) >> 6;
    int lane = threadIdx.x & 63;
    if (w >= NN) return;
    int start = starts[w], end = ends[w];
    int g = lane >> 4, q = lane & 15;
    const char* Gb = (const char*)G1;
    int qb = q << 4;  // byte offset within row
    float a0 = 0.f, a1 = 0.f, a2 = 0.f, a3 = 0.f, a4 = 0.f, a5 = 0.f, a6 = 0.f, a7 = 0.f;
    for (int base = start; base < end; base += 64) {
        int cnt = min(64, end - base);
        int idx = (base + lane < end) ? ssrc[base + lane] : 0;
        int j = 0;
        for (; j + 16 <= cnt; j += 16) {  // 16 edges: 4 gathers in flight
            int s0 = __shfl(idx, j + g, 64);
            int s1 = __shfl(idx, j + 4 + g, 64);
            int s2 = __shfl(idx, j + 8 + g, 64);
            int s3 = __shfl(idx, j + 12 + g, 64);
            uint4 u0 = *(const uint4*)(Gb + (s0 << 8) + qb);
            uint4 u1 = *(const uint4*)(Gb + (s1 << 8) + qb);
            uint4 u2 = *(const uint4*)(Gb + (s2 << 8) + qb);
            uint4 u3 = *(const uint4*)(Gb + (s3 << 8) + qb);
            a0 += (lo16(u0.x) + lo16(u1.x)) + (lo16(u2.x) + lo16(u3.x));
            a1 += (hi16(u0.x) + hi16(u1.x)) + (hi16(u2.x) + hi16(u3.x));
            a2 += (lo16(u0.y) + lo16(u1.y)) + (lo16(u2.y) + lo16(u3.y));
            a3 += (hi16(u0.y) + hi16(u1.y)) + (hi16(u2.y) + hi16(u3.y));
            a4 += (lo16(u0.z) + lo16(u1.z)) + (lo16(u2.z) + lo16(u3.z));
            a5 += (hi16(u0.z) + hi16(u1.z)) + (hi16(u2.z) + hi16(u3.z));
            a6 += (lo16(u0.w) + lo16(u1.w)) + (lo16(u2.w) + lo16(u3.w));
            a7 += (hi16(u0.w) + hi16(u1.w)) + (hi16(u2.w) + hi16(u3.w));
        }
        for (; j + 8 <= cnt; j += 8) {  // 8 edges: 2 gathers in flight
            int s0 = __shfl(idx, j + g, 64);
            int s1 = __shfl(idx, j + 4 + g, 64);
            uint4 u0 = *(const uint4*)(Gb + (s0 << 8) + qb);
            uint4 u1 = *(const uint4*)(Gb + (s1 << 8) + qb);
            a0 += lo16(u0.x) + lo16(u1.x);
            a1 += hi16(u0.x) + hi16(u1.x);
            a2 += lo16(u0.y) + lo16(u1.y);
            a3 += hi16(u0.y) + hi16(u1.y);
            a4 += lo16(u0.z) + lo16(u1.z);
            a5 += hi16(u0.z) + hi16(u1.z);
            a6 += lo16(u0.w) + lo16(u1.w);
            a7 += hi16(u0.w) + hi16(u1.w);
        }
        for (; j < cnt; j += 4) {  // tail: up to 4 edges, predicated per group
            int e = j + g;
            int s0 = __shfl(idx, (e < cnt) ? e : 0, 64);
            if (e < cnt) {
                uint4 u0 = *(const uint4*)(Gb + (s0 << 8) + qb);
                a0 += lo16(u0.x); a1 += hi16(u0.x);
                a2 += lo16(u0.y); a3 += hi16(u0.y);
                a4 += lo16(u0.z); a5 += hi16(u0.z);
                a6 += lo16(u0.w); a7 += hi16(u0.w);
            }
        }
    }
    a0 += __shfl_xor(a0, 16, 64); a0 += __shfl_xor(a0, 32, 64);
    a1 += __shfl_xor(a1, 16, 64); a1 += __shfl_xor(a1, 32, 64);
    a2 += __shfl_xor(a2, 16, 64); a2 += __shfl_xor(a2, 32, 64);
    a3 += __shfl_xor(a3, 16, 64); a3 += __shfl_xor(a3, 32, 64);
    a4 += __shfl_xor(a4, 16, 64); a4 += __shfl_xor(a4, 32, 64);
    a5 += __shfl_xor(a5, 16, 64); a5 += __shfl_xor(a5, 32, 64);
    a6 += __shfl_xor(a6, 16, 64); a6 += __shfl_xor(a6, 32, 64);
    a7 += __shfl_xor(a7, 16, 64); a7 += __shfl_xor(a7, 32, 64);
    if (g == 0) {
        float inv = 1.0f / fmaxf((float)(end - start), 1.0f);
        uint4 rv = *(const uint4*)((const char*)C1root + (size_t)w * 256 + qb);
        float4 c0 = *(const float4*)(b1 + q * 8);
        float4 c1 = *(const float4*)(b1 + q * 8 + 4);
        float h0 = fmaxf(a0 * inv + c0.x + lo16(rv.x), 0.f);
        float h1 = fmaxf(a1 * inv + c0.y + hi16(rv.x), 0.f);
        float h2 = fmaxf(a2 * inv + c0.z + lo16(rv.y), 0.f);
        float h3 = fmaxf(a3 * inv + c0.w + hi16(rv.y), 0.f);
        float h4 = fmaxf(a4 * inv + c1.x + lo16(rv.z), 0.f);
        float h5 = fmaxf(a5 * inv + c1.y + hi16(rv.z), 0.f);
        float h6 = fmaxf(a6 * inv + c1.z + lo16(rv.w), 0.f);
        float h7 = fmaxf(a7 * inv + c1.w + hi16(rv.w), 0.f);
        uint4 o;
        o.x = ((uint_t)f2bf(h1) << 16) | (uint_t)f2bf(h0);
        o.y = ((uint_t)f2bf(h3) << 16) | (uint_t)f2bf(h2);
        o.z = ((uint_t)f2bf(h5) << 16) | (uint_t)f2bf(h4);
        o.w = ((uint_t)f2bf(h7) << 16) | (uint_t)f2bf(h6);
        *(uint4*)((char*)s1b + (size_t)w * 256 + qb) = o;
    }
}

// ---------------- aggregate layer 2 + log_softmax
__global__ __launch_bounds__(256) void aggregate2(const int* __restrict__ starts,
                                                  const int* __restrict__ ends,
                                                  const int* __restrict__ ssrc,
                                                  const ushort_t* __restrict__ G2a,
                                                  const ushort_t* __restrict__ G2b,
                                                  const ushort_t* __restrict__ C2root,
                                                  const float* __restrict__ b2,
                                                  float* __restrict__ out) {
    int w = (blockIdx.x * blockDim.x + threadIdx.x) >> 6;
    int lane = threadIdx.x & 63;
    if (w >= NN) return;
    int start = starts[w], end = ends[w];
    int g = lane >> 4, q = lane & 15;
    bool act = q < 10;
    const char* tbl;
    int rsh, off0;
    if (q < 8) { tbl = (const char*)G2a; rsh = 6; off0 = q * 8; }
    else       { tbl = (const char*)G2b; rsh = 4; off0 = (q - 8) * 8; }
    float a0 = 0.f, a1 = 0.f, a2 = 0.f, a3 = 0.f;
    for (int base = start; base < end; base += 64) {
        int cnt = min(64, end - base);
        int idx = (base + lane < end) ? ssrc[base + lane] : 0;
        int j = 0;
        for (; j + 16 <= cnt; j += 16) {
            int s0 = __shfl(idx, j + g, 64);
            int s1 = __shfl(idx, j + 4 + g, 64);
            int s2 = __shfl(idx, j + 8 + g, 64);
            int s3 = __shfl(idx, j + 12 + g, 64);
            if (act) {
                uint2 u0 = *(const uint2*)(tbl + ((size_t)s0 << rsh) + off0);
                uint2 u1 = *(const uint2*)(tbl + ((size_t)s1 << rsh) + off0);
                uint2 u2 = *(const uint2*)(tbl + ((size_t)s2 << rsh) + off0);
                uint2 u3 = *(const uint2*)(tbl + ((size_t)s3 << rsh) + off0);
                a0 += (lo16(u0.x) + lo16(u1.x)) + (lo16(u2.x) + lo16(u3.x));
                a1 += (hi16(u0.x) + hi16(u1.x)) + (hi16(u2.x) + hi16(u3.x));
                a2 += (lo16(u0.y) + lo16(u1.y)) + (lo16(u2.y) + lo16(u3.y));
                a3 += (hi16(u0.y) + hi16(u1.y)) + (hi16(u2.y) + hi16(u3.y));
            }
        }
        for (; j + 8 <= cnt; j += 8) {
            int s0 = __shfl(idx, j + g, 64);
            int s1 = __shfl(idx, j + 4 + g, 64);
            if (act) {
                uint2 u0 = *(const uint2*)(tbl + ((size_t)s0 << rsh) + off0);
                uint2 u1 = *(const uint2*)(tbl + ((size_t)s1 << rsh) + off0);
                a0 += lo16(u0.x) + lo16(u1.x);
                a1 += hi16(u0.x) + hi16(u1.x);
                a2 += lo16(u0.y) + lo16(u1.y);
                a3 += hi16(u0.y) + hi16(u1.y);
            }
        }
        for (; j < cnt; j += 4) {
            int e = j + g;
            int s0 = __shfl(idx, (e < cnt) ? e : 0, 64);
            if (act && e < cnt) {
                uint2 u0 = *(const uint2*)(tbl + ((size_t)s0 << rsh) + off0);
                a0 += lo16(u0.x); a1 += hi16(u0.x);
                a2 += lo16(u0.y); a3 += hi16(u0.y);
            }
        }
    }
    a0 += __shfl_xor(a0, 16, 64); a0 += __shfl_xor(a0, 32, 64);
    a1 += __shfl_xor(a1, 16, 64); a1 += __shfl_xor(a1, 32, 64);
    a2 += __shfl_xor(a2, 16, 64); a2 += __shfl_xor(a2, 32, 64);
    a3 += __shfl_xor(a3, 16, 64); a3 += __shfl_xor(a3, 32, 64);
    if (g == 0) {
        float inv = 1.0f / fmaxf((float)(end - start), 1.0f);
        float v0 = -INFINITY, v1 = -INFINITY, v2 = -INFINITY, v3 = -INFINITY;
        if (act) {
            uint2 rv = *(const uint2*)((const char*)C2root + (size_t)w * 80 + (q << 3));
            float4 bb = *(const float4*)(b2 + q * 4);
            v0 = a0 * inv + bb.x + lo16(rv.x);
            v1 = a1 * inv + bb.y + hi16(rv.x);
            v2 = a2 * inv + bb.z + lo16(rv.y);
            v3 = a3 * inv + bb.w + hi16(rv.y);
        }
        float m = fmaxf(fmaxf(v0, v1), fmaxf(v2, v3));
#pragma unroll
        for (int d = 8; d >= 1; d >>= 1) m = fmaxf(m, __shfl_xor(m, d, 64));
        float e = act ? (expf(v0 - m) + expf(v1 - m)) + (expf(v2 - m) + expf(v3 - m)) : 0.f;
#pragma unroll
        for (int d = 8; d >= 1; d >>= 1) e += __shfl_xor(e, d, 64);
        float lse = m + logf(e);
        if (act) {
            float4 o = make_float4(v0 - lse, v1 - lse, v2 - lse, v3 - lse);
            *(float4*)(out + (size_t)w * 40 + q * 4) = o;
        }
    }
}

extern "C" void kernel_launch(void* const* d_in, const int* in_sizes, int n_in,
                              void* d_out, int out_size, void* d_ws, size_t ws_size,
                              hipStream_t stream) {
    const float* x   = (const float*)d_in[0];
    const int*   ei  = (const int*)d_in[1];
    const float* Wl1 = (const float*)d_in[2];
    const float* b1  = (const float*)d_in[3];
    const float* Wr1 = (const float*)d_in[4];
    const float* Wl2 = (const float*)d_in[5];
    const float* b2  = (const float*)d_in[6];
    const float* Wr2 = (const float*)d_in[7];
    float* out = (float*)d_out;

    char* ws = (char*)d_ws;
    size_t off = 0;
    auto alloc = [&](size_t bytes) -> void* {
        void* p = ws + off;
        off = (off + bytes + 255) & ~(size_t)255;
        return p;
    };
    int*      gcur    = (int*)alloc((size_t)NBUK * 4);
    int*      pairs   = (int*)alloc((size_t)NBUK * CAP * 4);   // padded buckets
    int*      starts  = (int*)alloc((size_t)NN * 4);
    int*      ends    = (int*)alloc((size_t)NN * 4);
    int*      ssrc    = (int*)alloc((size_t)NBUK * CAP * 4);   // padded buckets
    ushort_t* W1T     = (ushort_t*)alloc((size_t)256 * 128 * 2);
    ushort_t* W2T     = (ushort_t*)alloc((size_t)128 * 128 * 2);
    ushort_t* xb      = (ushort_t*)alloc(MPAD * 128 * 2);      // x in bf16, padded rows
    ushort_t* G1      = (ushort_t*)alloc((size_t)NN * 128 * 2);
    ushort_t* C1root  = (ushort_t*)alloc((size_t)NN * 128 * 2);
    ushort_t* s1b     = (ushort_t*)alloc(MPAD * 128 * 2);      // padded rows for gemm2
    ushort_t* G2a     = (ushort_t*)alloc((size_t)NN * 32 * 2); // ch 0-31, 64B rows
    ushort_t* G2b     = (ushort_t*)alloc((size_t)NN * 8 * 2);  // ch 32-39, 16B rows
    ushort_t* C2root  = (ushort_t*)alloc((size_t)NN * 40 * 2);

    front<<<FRONT_GRID, 256, 0, stream>>>(x, xb, Wl1, Wr1, Wl2, Wr2, W1T, W2T, gcur);
    bin_pass<<<NBLK_A, 256, 0, stream>>>(ei, gcur, pairs);
    sort_gemm1<<<NBUK + MT * 2, 256, 0, stream>>>(gcur, pairs, starts, ends, ssrc,
                                                  xb, W1T, G1, C1root);
    aggregate1<<<(NN * 64 + 255) / 256, 256, 0, stream>>>(starts, ends, ssrc, G1, C1root,
                                                          b1, s1b);
    gemm2_k<<<MT, 256, 0, stream>>>(s1b, W2T, G2a, G2b, C2root);
    aggregate2<<<(NN * 64 + 255) / 256, 256, 0, stream>>>(starts, ends, ssrc, G2a, G2b,
                                                          C2root, b2, out);
}

// Round 12
// 283.784 us; speedup vs baseline: 2.2808x; 1.0560x over previous
//
#include <hip/hip_runtime.h>
#include <math.h>

#define NN 100000
#define NE 1600000
#define NBUK ((NN + 255) / 256)      // 391 buckets of 256 nodes
#define CAP 5120                     // bucket capacity (mean 4096, +16 sigma)
#define NBLK_A 500
#define EPB (NE / NBLK_A)            // 3200 edges per bin block
#define GPB (EPB / 4)                // 800 int4 groups
#define MT ((NN + 127) / 128)        // 782 M-tiles
#define MPAD ((size_t)MT * 128)      // 100096 padded rows for A operands
#define PACK_B 192                   // pack_weights blocks in front
#define FRONT_GRID 2048

typedef __attribute__((ext_vector_type(8))) short short8;
typedef __attribute__((ext_vector_type(4))) float f32x4;
typedef __attribute__((ext_vector_type(2))) float f32x2;
typedef __attribute__((ext_vector_type(4))) int i32x4;
typedef unsigned short ushort_t;
typedef unsigned int uint_t;
typedef unsigned char uchar_t;

__device__ inline ushort_t f2bf(float f) {  // RNE
    uint_t u = __builtin_bit_cast(uint_t, f);
    u += 0x7FFFu + ((u >> 16) & 1u);
    return (ushort_t)(u >> 16);
}
__device__ inline float bits2f(uint_t u) { return __builtin_bit_cast(float, u); }
__device__ inline float lo16(uint_t u) { return bits2f(u << 16); }
__device__ inline float hi16(uint_t u) { return bits2f(u & 0xFFFF0000u); }
__device__ inline uchar_t f2fp8(float f) {  // OCP e4m3fn via HW cvt (RNE)
    int p = __builtin_amdgcn_cvt_pk_fp8_f32(f, f, 0, false);
    return (uchar_t)(p & 0xFF);
}

__device__ inline void gload_lds16(const void* g, void* l) {
    __builtin_amdgcn_global_load_lds(
        (const __attribute__((address_space(1))) unsigned int*)g,
        (__attribute__((address_space(3))) unsigned int*)l, 16, 0, 0);
}

// ---------------- front: cvt x->bf16 | pack weights | init gcur (bucket bases)
__global__ __launch_bounds__(256) void front(const float* __restrict__ x,
                                             ushort_t* __restrict__ xb,
                                             const float* __restrict__ Wl1,
                                             const float* __restrict__ Wr1,
                                             const float* __restrict__ Wl2,
                                             const float* __restrict__ Wr2,
                                             ushort_t* __restrict__ W1T,
                                             ushort_t* __restrict__ W2T,
                                             int* __restrict__ gcur) {
    int bid = blockIdx.x, tid = threadIdx.x;
    if (bid == 0) {
        for (int i = tid; i < NBUK; i += 256) gcur[i] = i * CAP;
    }
    if (bid < PACK_B) {  // pack weights
        int gid = bid * 256 + tid;
        if (gid < 256 * 128) {
            int n = gid >> 7, k = gid & 127;
            float v = (n < 128) ? Wl1[k * 128 + n] : Wr1[k * 128 + (n - 128)];
            W1T[gid] = f2bf(v);
        } else {
            int g = gid - 256 * 128;
            if (g < 128 * 128) {
                int n = g >> 7, k = g & 127;
                float v = 0.0f;
                if (n < 40)      v = Wl2[k * 40 + n];
                else if (n < 80) v = Wr2[k * 40 + (n - 40)];
                W2T[g] = f2bf(v);
            }
        }
    } else {  // cvt x -> bf16, grid-stride over remaining blocks
        const int total = NN * 128 / 8;
        const int nb = FRONT_GRID - PACK_B;
        const f32x4* src = (const f32x4*)x;
        for (int g = (bid - PACK_B) * 256 + tid; g < total; g += nb * 256) {
            f32x4 v0 = __builtin_nontemporal_load(src + (size_t)g * 2);
            f32x4 v1 = __builtin_nontemporal_load(src + (size_t)g * 2 + 1);
            i32x4 o;
            o[0] = ((uint_t)f2bf(v0[1]) << 16) | (uint_t)f2bf(v0[0]);
            o[1] = ((uint_t)f2bf(v0[3]) << 16) | (uint_t)f2bf(v0[2]);
            o[2] = ((uint_t)f2bf(v1[1]) << 16) | (uint_t)f2bf(v1[0]);
            o[3] = ((uint_t)f2bf(v1[3]) << 16) | (uint_t)f2bf(v1[2]);
            *(i32x4*)(xb + (size_t)g * 8) = o;
        }
    }
}

// ---------------- CSR: bin edges into PADDED bucket runs (stride CAP).
__global__ __launch_bounds__(256) void bin_pass(const int* __restrict__ ei,
                                                int* __restrict__ gcur,
                                                int* __restrict__ pairs) {
    __shared__ int h[NBUK];
    __shared__ int base[NBUK];
    int bid = blockIdx.x, tid = threadIdx.x;
    for (int i = tid; i < NBUK; i += 256) h[i] = 0;
    __syncthreads();
    int e0 = bid * EPB;
    const i32x4* dsts = (const i32x4*)(ei + NE + e0);
    const i32x4* srcs = (const i32x4*)(ei + e0);
    for (int g = tid; g < GPB; g += 256) {
        i32x4 d = __builtin_nontemporal_load(dsts + g);
#pragma unroll
        for (int j = 0; j < 4; ++j) atomicAdd(&h[d[j] >> 8], 1);
    }
    __syncthreads();
    for (int i = tid; i < NBUK; i += 256) {
        int c = h[i];
        base[i] = c ? atomicAdd(&gcur[i], c) : 0;
        h[i] = 0;  // reuse as run cursor
    }
    __syncthreads();
    for (int g = tid; g < GPB; g += 256) {
        i32x4 d = __builtin_nontemporal_load(dsts + g);
        i32x4 s = __builtin_nontemporal_load(srcs + g);
#pragma unroll
        for (int j = 0; j < 4; ++j) {
            int buk = d[j] >> 8;
            int pos = base[buk] + atomicAdd(&h[buk], 1);
            if (pos < (buk + 1) * CAP) pairs[pos] = (s[j] << 8) | (d[j] & 255);
        }
    }
}

// ---------------- shared GEMM tile: A[128,K=128]bf16 @ Bt^T, one-shot LDS stage.
//   LAYER 1: n<128 -> G1 fp8 e4m3 stride 128 (1 byte/elem); n<256 -> Croot bf16 stride 128
//   LAYER 2: n<32 -> O0 (G2a, stride 32); n<40 -> O1 (G2b, stride 8); n<80 -> Croot stride 40
template <int LAYER>
__device__ inline void gemm_tile(char* As, char* Bs,
                                 const ushort_t* __restrict__ A,
                                 const ushort_t* __restrict__ Bt,
                                 void* __restrict__ O0v,
                                 ushort_t* __restrict__ O1,
                                 ushort_t* __restrict__ Croot,
                                 int bx, int by, int tid) {
    int lane = tid & 63, wid = tid >> 6;
    int quad = lane >> 4, l15 = lane & 15;
    int wm = (wid & 1) * 64, wn = (wid >> 1) * 64;
    int mBase = bx * 128, nBase = by * 128;

    const char* aT = (const char*)(A + (size_t)mBase * 128);
    const char* bT = (const char*)(Bt + (size_t)nBase * 128);
#pragma unroll
    for (int ii = 0; ii < 8; ++ii) {
        int rr = (wid * 8 + ii) * 4 + quad;
        int src = rr * 256 + ((l15 * 16) ^ ((rr & 7) << 4));
        int ldsb = (wid * 8 + ii) * 1024;
        gload_lds16(aT + src, As + ldsb);
        gload_lds16(bT + src, Bs + ldsb);
    }
    asm volatile("s_waitcnt vmcnt(0)" ::: "memory");
    __syncthreads();

    f32x4 acc[4][4];
#pragma unroll
    for (int i = 0; i < 4; ++i)
#pragma unroll
        for (int j = 0; j < 4; ++j) acc[i][j] = (f32x4){0.f, 0.f, 0.f, 0.f};

#pragma unroll
    for (int kk = 0; kk < 4; ++kk) {
        int kByte = kk * 64 + quad * 16;
        short8 af[4], bfr[4];
#pragma unroll
        for (int i = 0; i < 4; ++i) {
            int row = wm + i * 16 + l15;
            af[i] = *(const short8*)(As + row * 256 + (kByte ^ ((row & 7) << 4)));
        }
#pragma unroll
        for (int j = 0; j < 4; ++j) {
            int row = wn + j * 16 + l15;
            bfr[j] = *(const short8*)(Bs + row * 256 + (kByte ^ ((row & 7) << 4)));
        }
#pragma unroll
        for (int i = 0; i < 4; ++i)
#pragma unroll
            for (int j = 0; j < 4; ++j)
                acc[i][j] = __builtin_amdgcn_mfma_f32_16x16x32_bf16(af[i], bfr[j],
                                                                    acc[i][j], 0, 0, 0);
    }

#pragma unroll
    for (int i = 0; i < 4; ++i) {
#pragma unroll
        for (int r = 0; r < 4; ++r) {
            int m = mBase + wm + i * 16 + quad * 4 + r;
            if (m >= NN) continue;
#pragma unroll
            for (int j = 0; j < 4; ++j) {
                int n = nBase + wn + j * 16 + l15;
                float v = acc[i][j][r];
                if (LAYER == 1) {
                    if (n < 128) ((uchar_t*)O0v)[(size_t)m * 128 + n] = f2fp8(v);
                    else O1[(size_t)m * 128 + (n - 128)] = f2bf(v);
                } else {
                    if (n < 32) ((ushort_t*)O0v)[(size_t)m * 32 + n] = f2bf(v);
                    else if (n < 40) O1[(size_t)m * 8 + (n - 32)] = f2bf(v);
                    else if (n < 80) Croot[(size_t)m * 40 + (n - 40)] = f2bf(v);
                }
            }
        }
    }
}

// ---------------- MERGED: per-bucket counting sort + layer-1 GEMM
__global__ __launch_bounds__(256, 2) void sort_gemm1(const int* __restrict__ gcur,
                                                     const int* __restrict__ pairs,
                                                     int* __restrict__ starts,
                                                     int* __restrict__ ends,
                                                     int* __restrict__ ssrc,
                                                     const ushort_t* __restrict__ A,
                                                     const ushort_t* __restrict__ Bt,
                                                     uchar_t* __restrict__ G,
                                                     ushort_t* __restrict__ Croot) {
    __shared__ __align__(16) char smem[65536];
    int bid = blockIdx.x, tid = threadIdx.x;
    if (bid < NBUK) {
        int* plds = (int*)smem;                 // CAP ints
        int* slds = (int*)(smem + CAP * 4);     // CAP ints
        int* cnt  = (int*)(smem + CAP * 8);     // 256 ints
        int* excl = cnt + 256;                  // 256 ints
        int buk = bid;
        int bstart = buk * CAP;
        int count = min(gcur[buk] - bstart, CAP);
        int lo = buk << 8;
        cnt[tid] = 0;
        __syncthreads();
        for (int j = tid; j < count; j += 256) {
            int p = pairs[bstart + j];
            plds[j] = p;
            atomicAdd(&cnt[p & 255], 1);
        }
        __syncthreads();
        int c = cnt[tid];
        excl[tid] = c;
        __syncthreads();
        for (int d = 1; d < 256; d <<= 1) {
            int tmp = (tid >= d) ? excl[tid - d] : 0;
            __syncthreads();
            excl[tid] += tmp;
            __syncthreads();
        }
        int myExcl = excl[tid] - c;
        __syncthreads();
        excl[tid] = myExcl;
        cnt[tid] = 0;  // reuse as scatter cursor
        __syncthreads();
        for (int j = tid; j < count; j += 256) {
            int p = plds[j];
            int loc = p & 255;
            int pos = excl[loc] + atomicAdd(&cnt[loc], 1);
            slds[pos] = p >> 8;
        }
        __syncthreads();
        for (int j = tid; j < count; j += 256) ssrc[bstart + j] = slds[j];
        if (lo + tid < NN) {
            starts[lo + tid] = bstart + myExcl;
            ends[lo + tid]   = bstart + myExcl + c;
        }
    } else {
        int gb = bid - NBUK;
        int bx = gb % MT, by = gb / MT;
        gemm_tile<1>(smem, smem + 32768, A, Bt, (void*)G, Croot, (ushort_t*)nullptr, bx, by, tid);
    }
}

// ---------------- layer-2 GEMM (split G2a/G2b output)
__global__ __launch_bounds__(256, 2) void gemm2_k(const ushort_t* __restrict__ A,
                                                  const ushort_t* __restrict__ Bt,
                                                  ushort_t* __restrict__ G2a,
                                                  ushort_t* __restrict__ G2b,
                                                  ushort_t* __restrict__ C2root) {
    __shared__ __align__(16) char smem[65536];
    gemm_tile<2>(smem, smem + 32768, A, Bt, (void*)G2a, G2b, C2root, blockIdx.x, 0, threadIdx.x);
}

// ---------------- aggregate layer 1: QUARTER-WAVE edge parallelism, fp8 G1
// (128B rows = exactly one cache line per gather; bytes are the proven lever).
__global__ __launch_bounds__(256) void aggregate1(const int* __restrict__ starts,
                                                  const int* __restrict__ ends,
                                                  const int* __restrict__ ssrc,
                                                  const uchar_t* __restrict__ G1,
                                                  const ushort_t* __restrict__ C1root,
                                                  const float* __restrict__ b1,
                                                  ushort_t* __restrict__ s1b) {
    int w = (blockIdx.x * blockDim.x + threadIdx.x) >> 6;
    int lane = threadIdx.x & 63;
    if (w >= NN) return;
    int start = starts[w], end = ends[w];
    int g = lane >> 4, q = lane & 15;
    const char* Gb = (const char*)G1;
    int qb8 = q << 3;  // byte offset within 128B fp8 row (8 channels/lane)
    float a0 = 0.f, a1 = 0.f, a2 = 0.f, a3 = 0.f, a4 = 0.f, a5 = 0.f, a6 = 0.f, a7 = 0.f;
    for (int base = start; base < end; base += 64) {
        int cnt = min(64, end - base);
        int idx = (base + lane < end) ? ssrc[base + lane] : 0;
        int j = 0;
        for (; j + 16 <= cnt; j += 16) {  // 16 edges: 4 gathers in flight
            int s0 = __shfl(idx, j + g, 64);
            int s1 = __shfl(idx, j + 4 + g, 64);
            int s2 = __shfl(idx, j + 8 + g, 64);
            int s3 = __shfl(idx, j + 12 + g, 64);
            uint2 u0 = *(const uint2*)(Gb + (s0 << 7) + qb8);
            uint2 u1 = *(const uint2*)(Gb + (s1 << 7) + qb8);
            uint2 u2 = *(const uint2*)(Gb + (s2 << 7) + qb8);
            uint2 u3 = *(const uint2*)(Gb + (s3 << 7) + qb8);
#pragma unroll
            for (int t = 0; t < 4; ++t) {
                uint2 u = (t == 0) ? u0 : (t == 1) ? u1 : (t == 2) ? u2 : u3;
                f32x2 p0 = __builtin_amdgcn_cvt_pk_f32_fp8(u.x, false);
                f32x2 p1 = __builtin_amdgcn_cvt_pk_f32_fp8(u.x, true);
                f32x2 p2 = __builtin_amdgcn_cvt_pk_f32_fp8(u.y, false);
                f32x2 p3 = __builtin_amdgcn_cvt_pk_f32_fp8(u.y, true);
                a0 += p0.x; a1 += p0.y; a2 += p1.x; a3 += p1.y;
                a4 += p2.x; a5 += p2.y; a6 += p3.x; a7 += p3.y;
            }
        }
        for (; j + 8 <= cnt; j += 8) {  // 8 edges: 2 gathers in flight
            int s0 = __shfl(idx, j + g, 64);
            int s1 = __shfl(idx, j + 4 + g, 64);
            uint2 u0 = *(const uint2*)(Gb + (s0 << 7) + qb8);
            uint2 u1 = *(const uint2*)(Gb + (s1 << 7) + qb8);
#pragma unroll
            for (int t = 0; t < 2; ++t) {
                uint2 u = (t == 0) ? u0 : u1;
                f32x2 p0 = __builtin_amdgcn_cvt_pk_f32_fp8(u.x, false);
                f32x2 p1 = __builtin_amdgcn_cvt_pk_f32_fp8(u.x, true);
                f32x2 p2 = __builtin_amdgcn_cvt_pk_f32_fp8(u.y, false);
                f32x2 p3 = __builtin_amdgcn_cvt_pk_f32_fp8(u.y, true);
                a0 += p0.x; a1 += p0.y; a2 += p1.x; a3 += p1.y;
                a4 += p2.x; a5 += p2.y; a6 += p3.x; a7 += p3.y;
            }
        }
        for (; j < cnt; j += 4) {  // tail: up to 4 edges, predicated per group
            int e = j + g;
            int s0 = __shfl(idx, (e < cnt) ? e : 0, 64);
            if (e < cnt) {
                uint2 u = *(const uint2*)(Gb + (s0 << 7) + qb8);
                f32x2 p0 = __builtin_amdgcn_cvt_pk_f32_fp8(u.x, false);
                f32x2 p1 = __builtin_amdgcn_cvt_pk_f32_fp8(u.x, true);
                f32x2 p2 = __builtin_amdgcn_cvt_pk_f32_fp8(u.y, false);
                f32x2 p3 = __builtin_amdgcn_cvt_pk_f32_fp8(u.y, true);
                a0 += p0.x; a1 += p0.y; a2 += p1.x; a3 += p1.y;
                a4 += p2.x; a5 += p2.y; a6 += p3.x; a7 += p3.y;
            }
        }
    }
    a0 += __shfl_xor(a0, 16, 64); a0 += __shfl_xor(a0, 32, 64);
    a1 += __shfl_xor(a1, 16, 64); a1 += __shfl_xor(a1, 32, 64);
    a2 += __shfl_xor(a2, 16, 64); a2 += __shfl_xor(a2, 32, 64);
    a3 += __shfl_xor(a3, 16, 64); a3 += __shfl_xor(a3, 32, 64);
    a4 += __shfl_xor(a4, 16, 64); a4 += __shfl_xor(a4, 32, 64);
    a5 += __shfl_xor(a5, 16, 64); a5 += __shfl_xor(a5, 32, 64);
    a6 += __shfl_xor(a6, 16, 64); a6 += __shfl_xor(a6, 32, 64);
    a7 += __shfl_xor(a7, 16, 64); a7 += __shfl_xor(a7, 32, 64);
    if (g == 0) {
        float inv = 1.0f / fmaxf((float)(end - start), 1.0f);
        uint4 rv = *(const uint4*)((const char*)C1root + (size_t)w * 256 + (q << 4));
        float4 c0 = *(const float4*)(b1 + q * 8);
        float4 c1 = *(const float4*)(b1 + q * 8 + 4);
        float h0 = fmaxf(a0 * inv + c0.x + lo16(rv.x), 0.f);
        float h1 = fmaxf(a1 * inv + c0.y + hi16(rv.x), 0.f);
        float h2 = fmaxf(a2 * inv + c0.z + lo16(rv.y), 0.f);
        float h3 = fmaxf(a3 * inv + c0.w + hi16(rv.y), 0.f);
        float h4 = fmaxf(a4 * inv + c1.x + lo16(rv.z), 0.f);
        float h5 = fmaxf(a5 * inv + c1.y + hi16(rv.z), 0.f);
        float h6 = fmaxf(a6 * inv + c1.z + lo16(rv.w), 0.f);
        float h7 = fmaxf(a7 * inv + c1.w + hi16(rv.w), 0.f);
        uint4 o;
        o.x = ((uint_t)f2bf(h1) << 16) | (uint_t)f2bf(h0);
        o.y = ((uint_t)f2bf(h3) << 16) | (uint_t)f2bf(h2);
        o.z = ((uint_t)f2bf(h5) << 16) | (uint_t)f2bf(h4);
        o.w = ((uint_t)f2bf(h7) << 16) | (uint_t)f2bf(h6);
        *(uint4*)((char*)s1b + (size_t)w * 256 + (q << 4)) = o;
    }
}

// ---------------- aggregate layer 2 + log_softmax
__global__ __launch_bounds__(256) void aggregate2(const int* __restrict__ starts,
                                                  const int* __restrict__ ends,
                                                  const int* __restrict__ ssrc,
                                                  const ushort_t* __restrict__ G2a,
                                                  const ushort_t* __restrict__ G2b,
                                                  const ushort_t* __restrict__ C2root,
                                                  const float* __restrict__ b2,
                                                  float* __restrict__ out) {
    int w = (blockIdx.x * blockDim.x + threadIdx.x) >> 6;
    int lane = threadIdx.x & 63;
    if (w >= NN) return;
    int start = starts[w], end = ends[w];
    int g = lane >> 4, q = lane & 15;
    bool act = q < 10;
    const char* tbl;
    int rsh, off0;
    if (q < 8) { tbl = (const char*)G2a; rsh = 6; off0 = q * 8; }
    else       { tbl = (const char*)G2b; rsh = 4; off0 = (q - 8) * 8; }
    float a0 = 0.f, a1 = 0.f, a2 = 0.f, a3 = 0.f;
    for (int base = start; base < end; base += 64) {
        int cnt = min(64, end - base);
        int idx = (base + lane < end) ? ssrc[base + lane] : 0;
        int j = 0;
        for (; j + 16 <= cnt; j += 16) {
            int s0 = __shfl(idx, j + g, 64);
            int s1 = __shfl(idx, j + 4 + g, 64);
            int s2 = __shfl(idx, j + 8 + g, 64);
            int s3 = __shfl(idx, j + 12 + g, 64);
            if (act) {
                uint2 u0 = *(const uint2*)(tbl + ((size_t)s0 << rsh) + off0);
                uint2 u1 = *(const uint2*)(tbl + ((size_t)s1 << rsh) + off0);
                uint2 u2 = *(const uint2*)(tbl + ((size_t)s2 << rsh) + off0);
                uint2 u3 = *(const uint2*)(tbl + ((size_t)s3 << rsh) + off0);
                a0 += (lo16(u0.x) + lo16(u1.x)) + (lo16(u2.x) + lo16(u3.x));
                a1 += (hi16(u0.x) + hi16(u1.x)) + (hi16(u2.x) + hi16(u3.x));
                a2 += (lo16(u0.y) + lo16(u1.y)) + (lo16(u2.y) + lo16(u3.y));
                a3 += (hi16(u0.y) + hi16(u1.y)) + (hi16(u2.y) + hi16(u3.y));
            }
        }
        for (; j + 8 <= cnt; j += 8) {
            int s0 = __shfl(idx, j + g, 64);
            int s1 = __shfl(idx, j + 4 + g, 64);
            if (act) {
                uint2 u0 = *(const uint2*)(tbl + ((size_t)s0 << rsh) + off0);
                uint2 u1 = *(const uint2*)(tbl + ((size_t)s1 << rsh) + off0);
                a0 += lo16(u0.x) + lo16(u1.x);
                a1 += hi16(u0.x) + hi16(u1.x);
                a2 += lo16(u0.y) + lo16(u1.y);
                a3 += hi16(u0.y) + hi16(u1.y);
            }
        }
        for (; j < cnt; j += 4) {
            int e = j + g;
            int s0 = __shfl(idx, (e < cnt) ? e : 0, 64);
            if (act && e < cnt) {
                uint2 u0 = *(const uint2*)(tbl + ((size_t)s0 << rsh) + off0);
                a0 += lo16(u0.x); a1 += hi16(u0.x);
                a2 += lo16(u0.y); a3 += hi16(u0.y);
            }
        }
    }
    a0 += __shfl_xor(a0, 16, 64); a0 += __shfl_xor(a0, 32, 64);
    a1 += __shfl_xor(a1, 16, 64); a1 += __shfl_xor(a1, 32, 64);
    a2 += __shfl_xor(a2, 16, 64); a2 += __shfl_xor(a2, 32, 64);
    a3 += __shfl_xor(a3, 16, 64); a3 += __shfl_xor(a3, 32, 64);
    if (g == 0) {
        float inv = 1.0f / fmaxf((float)(end - start), 1.0f);
        float v0 = -INFINITY, v1 = -INFINITY, v2 = -INFINITY, v3 = -INFINITY;
        if (act) {
            uint2 rv = *(const uint2*)((const char*)C2root + (size_t)w * 80 + (q << 3));
            float4 bb = *(const float4*)(b2 + q * 4);
            v0 = a0 * inv + bb.x + lo16(rv.x);
            v1 = a1 * inv + bb.y + hi16(rv.x);
            v2 = a2 * inv + bb.z + lo16(rv.y);
            v3 = a3 * inv + bb.w + hi16(rv.y);
        }
        float m = fmaxf(fmaxf(v0, v1), fmaxf(v2, v3));
#pragma unroll
        for (int d = 8; d >= 1; d >>= 1) m = fmaxf(m, __shfl_xor(m, d, 64));
        float e = act ? (expf(v0 - m) + expf(v1 - m)) + (expf(v2 - m) + expf(v3 - m)) : 0.f;
#pragma unroll
        for (int d = 8; d >= 1; d >>= 1) e += __shfl_xor(e, d, 64);
        float lse = m + logf(e);
        if (act) {
            float4 o = make_float4(v0 - lse, v1 - lse, v2 - lse, v3 - lse);
            *(float4*)(out + (size_t)w * 40 + q * 4) = o;
        }
    }
}

extern "C" void kernel_launch(void* const* d_in, const int* in_sizes, int n_in,
                              void* d_out, int out_size, void* d_ws, size_t ws_size,
                              hipStream_t stream) {
    const float* x   = (const float*)d_in[0];
    const int*   ei  = (const int*)d_in[1];
    const float* Wl1 = (const float*)d_in[2];
    const float* b1  = (const float*)d_in[3];
    const float* Wr1 = (const float*)d_in[4];
    const float* Wl2 = (const float*)d_in[5];
    const float* b2  = (const float*)d_in[6];
    const float* Wr2 = (const float*)d_in[7];
    float* out = (float*)d_out;

    char* ws = (char*)d_ws;
    size_t off = 0;
    auto alloc = [&](size_t bytes) -> void* {
        void* p = ws + off;
        off = (off + bytes + 255) & ~(size_t)255;
        return p;
    };
    int*      gcur    = (int*)alloc((size_t)NBUK * 4);
    int*      pairs   = (int*)alloc((size_t)NBUK * CAP * 4);   // padded buckets
    int*      starts  = (int*)alloc((size_t)NN * 4);
    int*      ends    = (int*)alloc((size_t)NN * 4);
    int*      ssrc    = (int*)alloc((size_t)NBUK * CAP * 4);   // padded buckets
    ushort_t* W1T     = (ushort_t*)alloc((size_t)256 * 128 * 2);
    ushort_t* W2T     = (ushort_t*)alloc((size_t)128 * 128 * 2);
    ushort_t* xb      = (ushort_t*)alloc(MPAD * 128 * 2);      // x in bf16, padded rows
    uchar_t*  G1      = (uchar_t*)alloc((size_t)NN * 128);     // fp8 e4m3, 128B rows
    ushort_t* C1root  = (ushort_t*)alloc((size_t)NN * 128 * 2);
    ushort_t* s1b     = (ushort_t*)alloc(MPAD * 128 * 2);      // padded rows for gemm2
    ushort_t* G2a     = (ushort_t*)alloc((size_t)NN * 32 * 2); // ch 0-31, 64B rows
    ushort_t* G2b     = (ushort_t*)alloc((size_t)NN * 8 * 2);  // ch 32-39, 16B rows
    ushort_t* C2root  = (ushort_t*)alloc((size_t)NN * 40 * 2);

    front<<<FRONT_GRID, 256, 0, stream>>>(x, xb, Wl1, Wr1, Wl2, Wr2, W1T, W2T, gcur);
    bin_pass<<<NBLK_A, 256, 0, stream>>>(ei, gcur, pairs);
    sort_gemm1<<<NBUK + MT * 2, 256, 0, stream>>>(gcur, pairs, starts, ends, ssrc,
                                                  xb, W1T, G1, C1root);
    aggregate1<<<(NN * 64 + 255) / 256, 256, 0, stream>>>(starts, ends, ssrc, G1, C1root,
                                                          b1, s1b);
    gemm2_k<<<MT, 256, 0, stream>>>(s1b, W2T, G2a, G2b, C2root);
    aggregate2<<<(NN * 64 + 255) / 256, 256, 0, stream>>>(starts, ends, ssrc, G2a, G2b,
                                                          C2root, b2, out);
}